// Round 1
// baseline (2713.002 us; speedup 1.0000x reference)
//
#include <hip/hip_runtime.h>
#include <math.h>

// Problem constants (hard-coded from setup_inputs): B=8, L=512, D=1024, H=16, C=4, Dk=64
#define BB 8
#define LL 512
#define DD 1024
#define HH 16
#define CC 4
#define DK 64
#define NEG_DPI 201.06192982974676f   // 64 * pi

// ---------------- reduction helpers ----------------
__device__ inline float block_sum256(float v, float* s_red) {
    int t = threadIdx.x;
    s_red[t] = v; __syncthreads();
    for (int off = 128; off > 0; off >>= 1) {
        if (t < off) s_red[t] += s_red[t + off];
        __syncthreads();
    }
    float r = s_red[0]; __syncthreads();
    return r;
}
__device__ inline float block_max256(float v, float* s_red) {
    int t = threadIdx.x;
    s_red[t] = v; __syncthreads();
    for (int off = 128; off > 0; off >>= 1) {
        if (t < off) s_red[t] = fmaxf(s_red[t], s_red[t + off]);
        __syncthreads();
    }
    float r = s_red[0]; __syncthreads();
    return r;
}
// monotone float<->uint encoding for atomicMax on floats (works for any finite value)
__device__ inline unsigned int fenc(float f) {
    unsigned int b = __float_as_uint(f);
    return (b & 0x80000000u) ? ~b : (b | 0x80000000u);
}
__device__ inline float fdec(unsigned int u) {
    return (u & 0x80000000u) ? __uint_as_float(u ^ 0x80000000u) : __uint_as_float(~u);
}

// ---------------- SGEMM: C[M,N] = A[M,K] @ W[K,N] + bias[N]  (M=4096,N=1024,K=1024) ----------------
__global__ __launch_bounds__(256)
void sgemm_bias(const float* __restrict__ A, const float* __restrict__ W,
                const float* __restrict__ bias, float* __restrict__ C) {
    const int M = BB * LL, N = DD, K = DD;
    __shared__ float As[16][65];
    __shared__ float Bs[16][65];
    int t = threadIdx.x;
    int n0 = blockIdx.x * 64, m0 = blockIdx.y * 64;
    int ty = t >> 4, tx = t & 15;
    float acc[4][4] = {};
    for (int k0 = 0; k0 < K; k0 += 16) {
#pragma unroll
        for (int i = 0; i < 4; i++) {
            int e = t + i * 256;
            int mm = e >> 4, kk = e & 15;
            As[kk][mm] = A[(size_t)(m0 + mm) * K + k0 + kk];
        }
#pragma unroll
        for (int i = 0; i < 4; i++) {
            int e = t + i * 256;
            int kk = e >> 6, nn = e & 63;
            Bs[kk][nn] = W[(size_t)(k0 + kk) * N + n0 + nn];
        }
        __syncthreads();
#pragma unroll
        for (int kk = 0; kk < 16; kk++) {
            float a[4], b[4];
#pragma unroll
            for (int i = 0; i < 4; i++) a[i] = As[kk][ty + 16 * i];
#pragma unroll
            for (int j = 0; j < 4; j++) b[j] = Bs[kk][tx + 16 * j];
#pragma unroll
            for (int i = 0; i < 4; i++)
#pragma unroll
                for (int j = 0; j < 4; j++) acc[i][j] += a[i] * b[j];
        }
        __syncthreads();
    }
#pragma unroll
    for (int i = 0; i < 4; i++) {
        int m = m0 + ty + 16 * i;
#pragma unroll
        for (int j = 0; j < 4; j++) {
            int n = n0 + tx + 16 * j;
            C[(size_t)m * N + n] = acc[i][j] + bias[n];
        }
    }
    (void)M;
}

// ---------------- alv = (A @ Wp + bias) transposed to (B,H,L) ----------------
__global__ __launch_bounds__(256)
void alv_gemm(const float* __restrict__ A, const float* __restrict__ Wp,
              const float* __restrict__ bias, float* __restrict__ alv) {
    __shared__ float As[16][65];
    __shared__ float Ws[64][17];
    int t = threadIdx.x;
    int m0 = blockIdx.x * 16;
    int r = t >> 4, hh = t & 15;
    float acc = 0.f;
    for (int kt = 0; kt < 16; kt++) {
        __syncthreads();
#pragma unroll
        for (int i = 0; i < 4; i++) {
            int e = t + i * 256;
            int rr = e >> 6, kk = e & 63;
            As[rr][kk] = A[(size_t)(m0 + rr) * DD + kt * 64 + kk];
        }
#pragma unroll
        for (int i = 0; i < 4; i++) {
            int e = t + i * 256;
            int kk = e >> 4, h2 = e & 15;
            Ws[kk][h2] = Wp[(size_t)(kt * 64 + kk) * HH + h2];
        }
        __syncthreads();
#pragma unroll
        for (int kk = 0; kk < 64; kk++) acc += As[r][kk] * Ws[kk][hh];
    }
    int m = m0 + r;
    int b = m >> 9, l = m & 511;
    alv[(size_t)(b * HH + hh) * LL + l] = acc + bias[hh];
}

// ---------------- clustering: cp, kl (atomic), optional log_pdf + global max ----------------
__global__ __launch_bounds__(256)
void cluster_kernel(const float* __restrict__ zsrc, const float* __restrict__ alv,
                    const float* __restrict__ mu, const float* __restrict__ logvar,
                    const float* __restrict__ logprior,
                    float* __restrict__ cp_out, float* __restrict__ lpdf_out,
                    unsigned int* __restrict__ maxenc, float* __restrict__ kl_out,
                    int isHead) {
    __shared__ float s_mu[CC * DK], s_iv[CC * DK], s_lv[CC * DK];
    __shared__ float s_slv[CC], s_siv[CC], s_lp[CC];
    __shared__ float s_red[256];
    int t = threadIdx.x;
    int tile = blockIdx.x & 1;
    int bh = blockIdx.x >> 1;
    int h = bh & (HH - 1), b = bh >> 4;
    int hm = isHead ? 0 : h;

    {
        float m = mu[hm * CC * DK + t];
        float lv = logvar[hm * CC * DK + t];
        s_mu[t] = m; s_lv[t] = lv; s_iv[t] = expf(-lv);
    }
    __syncthreads();
    if (t < CC) {
        float slv = 0.f, siv = 0.f;
        for (int d = 0; d < DK; d++) { slv += s_lv[t * DK + d]; siv += s_iv[t * DK + d]; }
        s_slv[t] = slv; s_siv[t] = siv;
    }
    if (t == CC) {
        float x[CC];
        float m = -1e30f;
        for (int c = 0; c < CC; c++) { x[c] = logprior[hm * CC + c]; m = fmaxf(m, x[c]); }
        float se = 0.f;
        for (int c = 0; c < CC; c++) se += expf(x[c] - m);
        float lse = m + logf(se);
        for (int c = 0; c < CC; c++) s_lp[c] = x[c] - lse;
    }
    __syncthreads();

    int l = tile * 256 + t;
    const float* zp = zsrc + ((size_t)(b * LL + l)) * DD + h * DK;
    float acc[CC] = {0.f, 0.f, 0.f, 0.f};
    for (int d = 0; d < DK; d += 4) {
        float4 z4 = *(const float4*)(zp + d);
#pragma unroll
        for (int c = 0; c < CC; c++) {
            float d0 = z4.x - s_mu[c * DK + d];     acc[c] += d0 * d0 * s_iv[c * DK + d];
            float d1 = z4.y - s_mu[c * DK + d + 1]; acc[c] += d1 * d1 * s_iv[c * DK + d + 1];
            float d2 = z4.z - s_mu[c * DK + d + 2]; acc[c] += d2 * d2 * s_iv[c * DK + d + 2];
            float d3 = z4.w - s_mu[c * DK + d + 3]; acc[c] += d3 * d3 * s_iv[c * DK + d + 3];
        }
    }
    float lpdf[CC];
#pragma unroll
    for (int c = 0; c < CC; c++)
        lpdf[c] = -0.5f * acc[c] - 0.5f * s_slv[c] - NEG_DPI + s_lp[c];
    float m = fmaxf(fmaxf(lpdf[0], lpdf[1]), fmaxf(lpdf[2], lpdf[3]));
    float se = 0.f;
#pragma unroll
    for (int c = 0; c < CC; c++) se += expf(lpdf[c] - m);
    float lse = m + logf(se);
    float lprob[CC], cpv[CC];
    size_t idx = ((size_t)(bh * LL + l)) * CC;
#pragma unroll
    for (int c = 0; c < CC; c++) {
        lprob[c] = lpdf[c] - lse;
        cpv[c] = expf(lprob[c]);
        cp_out[idx + c] = cpv[c];
    }
    if (isHead) {
#pragma unroll
        for (int c = 0; c < CC; c++) lpdf_out[idx + c] = lpdf[c];
    }
    float alvv = alv[(size_t)bh * LL + l];
    float avar = expf(alvv);
    float t1 = 0.f, t2 = 0.f;
#pragma unroll
    for (int c = 0; c < CC; c++) {
        t1 += expf(s_lp[c]) * (s_lp[c] - lprob[c]);
        t2 += cpv[c] * (acc[c] + avar * s_siv[c] + s_slv[c]);
    }
    float klv = t1 + 0.5f * t2 - 0.5f * (float)DK * (1.0f + alvv);
    float tot = block_sum256(klv, s_red);
    if (t == 0) atomicAdd(kl_out + b, tot * (1.0f / (HH * LL)));
    if (isHead) {
        float mt = block_max256(m, s_red);
        if (t == 0) atomicMax(maxenc, fenc(mt));
    }
}

// ---------------- pair stats: div loss (+ head: diagonal of log_softmax(aff)) ----------------
__global__ __launch_bounds__(256)
void pairstats_kernel(const float* __restrict__ cp, float* __restrict__ div_out,
                      float* __restrict__ mi_out, int isHead) {
    __shared__ float s_cp[LL * CC];
    __shared__ float s_red[256];
    int t = threadIdx.x;
    int bh = blockIdx.x;
    int b = bh >> 4;
    const float* base = cp + (size_t)bh * LL * CC;
#pragma unroll
    for (int i = 0; i < 8; i++) s_cp[t + i * 256] = base[t + i * 256];
    __syncthreads();
    float divacc = 0.f, diagacc = 0.f;
    for (int qi = 0; qi < 2; qi++) {
        int q = t + qi * 256;
        float c0 = s_cp[q * 4 + 0], c1 = s_cp[q * 4 + 1], c2 = s_cp[q * 4 + 2], c3 = s_cp[q * 4 + 3];
        float m = -1e30f, s = 0.f, selfdot = 0.f;
        for (int k = 0; k < LL; k++) {
            float dot = c0 * s_cp[k * 4 + 0] + c1 * s_cp[k * 4 + 1] + c2 * s_cp[k * 4 + 2] + c3 * s_cp[k * 4 + 3];
            float del = (k == q) ? 1.f : 0.f;
            float dd = dot - del;
            divacc += dd * dd * (del * 1.25f + (1.f - del) * 0.75f);
            if (isHead) {
                if (dot > m) { s = s * expf(m - dot) + 1.f; m = dot; }
                else         { s += expf(dot - m); }
                if (k == q) selfdot = dot;
            }
        }
        if (isHead) diagacc += selfdot - (m + logf(s));
    }
    float dtot = block_sum256(divacc, s_red);
    if (t == 0) atomicAdd(div_out + b, dtot * (1.0f / ((float)HH * LL * LL)));
    if (isHead) {
        float gtot = block_sum256(diagacc, s_red);
        if (t == 0) atomicAdd(mi_out + b, -gtot * (1.0f / (HH * LL)));
    }
}

// ---------------- fused attention: softmax * cluster_mask, renorm, ctx, attn mean ----------------
#define QT 8
__global__ __launch_bounds__(256)
void attn_kernel(const float* __restrict__ qb, const float* __restrict__ kb,
                 const float* __restrict__ vb, const float* __restrict__ cpq,
                 float* __restrict__ ctxf, float* __restrict__ attn_out) {
    __shared__ float s_z[QT * DK];        // 512
    __shared__ float s_kt[64 * 65];       // k/v tile, padded
    __shared__ float s_sc[QT * 520];      // score rows, padded stride
    __shared__ float s_cpk[LL * CC];      // 2048
    __shared__ float s_am[QT * LL];       // 4096 attn-mean accumulator
    int t = threadIdx.x;
    int b = blockIdx.x >> 6;
    int qt = blockIdx.x & 63;
    int q0 = qt * QT;
#pragma unroll
    for (int i = 0; i < 16; i++) s_am[t + i * 256] = 0.f;

    int rA = t >> 6;        // 0..3 (ctx slot rows rA and rA+4)
    int dA = t & 63;

    for (int h = 0; h < HH; h++) {
        __syncthreads();
        // stage q rows + cp(k) rows
#pragma unroll
        for (int i = 0; i < 2; i++) {
            int e = t + i * 256; int r = e >> 6, d = e & 63;
            s_z[e] = qb[((size_t)(b * LL + q0 + r)) * DD + h * DK + d];
        }
        const float* cpb = cpq + (size_t)(b * HH + h) * LL * CC;
#pragma unroll
        for (int i = 0; i < 8; i++) s_cpk[t + i * 256] = cpb[t + i * 256];

        // ---- scores ----
        for (int kt2 = 0; kt2 < 8; kt2++) {
            __syncthreads();
#pragma unroll
            for (int i = 0; i < 16; i++) {
                int e = t + i * 256; int kk = e >> 6, d = e & 63;
                s_kt[kk * 65 + d] = kb[((size_t)(b * LL + kt2 * 64 + kk)) * DD + h * DK + d];
            }
            __syncthreads();
            int r = t >> 5;
            int kk = t & 31;
            float dotA = 0.f, dotB = 0.f;
#pragma unroll
            for (int d = 0; d < DK; d++) {
                float zz = s_z[r * DK + d];
                dotA += zz * s_kt[kk * 65 + d];
                dotB += zz * s_kt[(kk + 32) * 65 + d];
            }
            s_sc[r * 520 + kt2 * 64 + kk]      = dotA * 0.125f;
            s_sc[r * 520 + kt2 * 64 + kk + 32] = dotB * 0.125f;
        }
        __syncthreads();

        // ---- softmax + mask + renorm per row (32 lanes per row) ----
        {
            int r = t >> 5, lane = t & 31;
            float cq0 = s_cpk[(q0 + r) * 4 + 0], cq1 = s_cpk[(q0 + r) * 4 + 1];
            float cq2 = s_cpk[(q0 + r) * 4 + 2], cq3 = s_cpk[(q0 + r) * 4 + 3];
            float m = -1e30f;
            for (int k = lane; k < LL; k += 32) m = fmaxf(m, s_sc[r * 520 + k]);
            for (int off = 16; off > 0; off >>= 1) m = fmaxf(m, __shfl_down(m, off, 32));
            m = __shfl(m, 0, 32);
            float Z = 0.f, S = 0.f;
            for (int k = lane; k < LL; k += 32) {
                float e = expf(s_sc[r * 520 + k] - m);
                float mask = cq0 * s_cpk[k * 4 + 0] + cq1 * s_cpk[k * 4 + 1]
                           + cq2 * s_cpk[k * 4 + 2] + cq3 * s_cpk[k * 4 + 3];
                float a = e * mask;
                Z += e; S += a;
                s_sc[r * 520 + k] = a;
            }
            for (int off = 16; off > 0; off >>= 1) {
                Z += __shfl_down(Z, off, 32);
                S += __shfl_down(S, off, 32);
            }
            Z = __shfl(Z, 0, 32); S = __shfl(S, 0, 32);
            float inv = 1.f / (S + 1e-6f * Z);
            for (int k = lane; k < LL; k += 32) {
                float a = s_sc[r * 520 + k] * inv;
                s_sc[r * 520 + k] = a;
                s_am[r * LL + k] += a * (1.f / (float)HH);
            }
        }

        // ---- ctx = attn @ vh (v tiles staged in LDS) ----
        float accA = 0.f, accB = 0.f;
        for (int kt2 = 0; kt2 < 8; kt2++) {
            __syncthreads();
#pragma unroll
            for (int i = 0; i < 16; i++) {
                int e = t + i * 256; int kk = e >> 6, d = e & 63;
                s_kt[kk * 65 + d] = vb[((size_t)(b * LL + kt2 * 64 + kk)) * DD + h * DK + d];
            }
            __syncthreads();
#pragma unroll
            for (int k2 = 0; k2 < 64; k2++) {
                float vv = s_kt[k2 * 65 + dA];
                accA += s_sc[rA * 520 + kt2 * 64 + k2] * vv;
                accB += s_sc[(rA + 4) * 520 + kt2 * 64 + k2] * vv;
            }
        }
        ctxf[((size_t)(b * LL + q0 + rA)) * DD + h * DK + dA] = accA;
        ctxf[((size_t)(b * LL + q0 + rA + 4)) * DD + h * DK + dA] = accB;
    }
    __syncthreads();
#pragma unroll
    for (int i = 0; i < 16; i++) {
        int e = t + i * 256; int r = e >> 9, k = e & 511;
        attn_out[((size_t)(b * LL + q0 + r)) * LL + k] = s_am[r * LL + k];
    }
}

// ---------------- MI: pdf + wsum ----------------
__global__ __launch_bounds__(256)
void wsum_kernel(const float* __restrict__ lpdf, const float* __restrict__ cp,
                 const unsigned int* __restrict__ maxenc,
                 float* __restrict__ pdf_out, float* __restrict__ wsum_out) {
    __shared__ float s_red[256];
    int t = threadIdx.x;
    int bh = blockIdx.x;
    float M = fdec(*maxenc);
    float a[CC] = {0.f, 0.f, 0.f, 0.f};
    for (int li = 0; li < 2; li++) {
        int l = t + li * 256;
        size_t idx = ((size_t)bh * LL + l) * CC;
        float p0 = expf(lpdf[idx + 0] - M);
        float p1 = expf(lpdf[idx + 1] - M);
        float p2 = expf(lpdf[idx + 2] - M);
        float p3 = expf(lpdf[idx + 3] - M);
        float pd = p0 + p1 + p2 + p3;
        pdf_out[(size_t)bh * LL + l] = pd;
        a[0] += cp[idx + 0] * pd; a[1] += cp[idx + 1] * pd;
        a[2] += cp[idx + 2] * pd; a[3] += cp[idx + 3] * pd;
    }
#pragma unroll
    for (int c = 0; c < CC; c++) {
        float tot = block_sum256(a[c], s_red);
        if (t == 0) wsum_out[bh * CC + c] = tot;
    }
}

// ---------------- MI: pairwise head overlap ----------------
__global__ __launch_bounds__(256)
void mi_kernel(const float* __restrict__ cp, const float* __restrict__ pdf,
               const float* __restrict__ wsum, float* __restrict__ mi_out) {
    __shared__ float s_q[HH * CC];   // mi_probs[i][c]
    __shared__ float s_c[HH * CC];   // cp[j][c]
    __shared__ float s_red[256];
    int t = threadIdx.x;
    int b = blockIdx.x >> 9;
    int l = blockIdx.x & 511;
    if (t < HH * CC) {
        int i = t >> 2, c = t & 3;
        float cpv = cp[((size_t)(b * HH + i) * LL + l) * CC + c];
        s_c[t] = cpv;
        float w = cpv * pdf[(size_t)(b * HH + i) * LL + l];
        float ws = wsum[(b * HH + i) * CC + c];
        s_q[t] = w / fmaxf(ws, 1e-6f);
    }
    __syncthreads();
    int i = t >> 4, j = t & 15;
    float sdot = 0.f;
#pragma unroll
    for (int c = 0; c < CC; c++) sdot += s_q[i * 4 + c] * s_c[j * 4 + c];
    float mi_p = fminf(sdot, 1.f);
    float val = (i != j) ? logf(1.f - mi_p + 1e-6f) : 0.f;
    float tot = block_sum256(val, s_red);
    if (t == 0) atomicAdd(mi_out + b, -10.f * tot * (1.0f / ((float)LL * HH * HH)));
}

// ---------------- launcher ----------------
extern "C" void kernel_launch(void* const* d_in, const int* in_sizes, int n_in,
                              void* d_out, int out_size, void* d_ws, size_t ws_size,
                              hipStream_t stream) {
    (void)in_sizes; (void)n_in; (void)out_size; (void)ws_size;
    const float* query  = (const float*)d_in[0];
    const float* key    = (const float*)d_in[1];
    const float* value  = (const float*)d_in[2];
    const float* Wq     = (const float*)d_in[3];
    const float* bq     = (const float*)d_in[4];
    const float* Wk     = (const float*)d_in[5];
    const float* bk     = (const float*)d_in[6];
    const float* Wv     = (const float*)d_in[7];
    const float* bv     = (const float*)d_in[8];
    const float* Wo     = (const float*)d_in[9];
    const float* bo     = (const float*)d_in[10];
    const float* Wsem   = (const float*)d_in[11];
    const float* bsem   = (const float*)d_in[12];
    const float* Whead  = (const float*)d_in[13];
    const float* bhead  = (const float*)d_in[14];
    const float* tokmu  = (const float*)d_in[15];
    const float* toklv  = (const float*)d_in[16];
    const float* toklp  = (const float*)d_in[17];
    const float* headmu = (const float*)d_in[18];
    const float* headlv = (const float*)d_in[19];
    const float* headlp = (const float*)d_in[20];

    float* ws   = (float*)d_ws;
    const size_t NBLD = (size_t)BB * LL * DD;      // 4194304
    float* q    = ws;
    float* k    = ws + NBLD;
    float* v    = ws + 2 * NBLD;
    float* ctxf = ws + 3 * NBLD;
    float* alvq = ws + 4 * NBLD;                    // 65536
    float* alvh = alvq + (size_t)BB * HH * LL;
    float* cpq  = alvh + (size_t)BB * HH * LL;      // 262144
    float* cph  = cpq + (size_t)BB * HH * LL * CC;
    float* lpdfh= cph + (size_t)BB * HH * LL * CC;
    float* pdfb = lpdfh + (size_t)BB * HH * LL * CC;
    float* wsumb= pdfb + (size_t)BB * HH * LL;
    unsigned int* maxenc = (unsigned int*)(wsumb + (size_t)BB * HH * CC);

    float* out      = (float*)d_out;
    float* attn_out = out + NBLD;
    float* kl_out   = attn_out + (size_t)BB * LL * LL;
    float* div_out  = kl_out + BB;
    float* mi_out   = div_out + BB;

    hipMemsetAsync(kl_out, 0, 3 * BB * sizeof(float), stream);
    hipMemsetAsync(maxenc, 0, sizeof(unsigned int), stream);

    dim3 gg(DD / 64, BB * LL / 64);  // (16, 64)
    sgemm_bias<<<gg, 256, 0, stream>>>(query, Wq, bq, q);
    sgemm_bias<<<gg, 256, 0, stream>>>(key,   Wk, bk, k);
    sgemm_bias<<<gg, 256, 0, stream>>>(value, Wv, bv, v);
    alv_gemm<<<BB * LL / 16, 256, 0, stream>>>(q, Wsem, bsem, alvq);
    cluster_kernel<<<BB * HH * 2, 256, 0, stream>>>(q, alvq, tokmu, toklv, toklp,
                                                    cpq, nullptr, nullptr, kl_out, 0);
    pairstats_kernel<<<BB * HH, 256, 0, stream>>>(cpq, div_out, nullptr, 0);
    attn_kernel<<<BB * (LL / QT), 256, 0, stream>>>(q, k, v, cpq, ctxf, attn_out);
    alv_gemm<<<BB * LL / 16, 256, 0, stream>>>(ctxf, Whead, bhead, alvh);
    cluster_kernel<<<BB * HH * 2, 256, 0, stream>>>(ctxf, alvh, headmu, headlv, headlp,
                                                    cph, lpdfh, maxenc, kl_out, 1);
    pairstats_kernel<<<BB * HH, 256, 0, stream>>>(cph, div_out, mi_out, 1);
    wsum_kernel<<<BB * HH, 256, 0, stream>>>(lpdfh, cph, maxenc, pdfb, wsumb);
    mi_kernel<<<BB * LL, 256, 0, stream>>>(cph, pdfb, wsumb, mi_out);
    sgemm_bias<<<gg, 256, 0, stream>>>(ctxf, Wo, bo, out);
}

// Round 2
// 1589.460 us; speedup vs baseline: 1.7069x; 1.7069x over previous
//
#include <hip/hip_runtime.h>
#include <math.h>

// Problem constants: B=8, L=512, D=1024, H=16, C=4, Dk=64
#define BB 8
#define LL 512
#define DD 1024
#define HH 16
#define CC 4
#define DK 64
#define NEG_DPI 201.06192982974676f   // 64 * pi

// ---------------- reduction helpers ----------------
__device__ inline float block_sum256(float v, float* s_red) {
    int t = threadIdx.x;
    s_red[t] = v; __syncthreads();
    for (int off = 128; off > 0; off >>= 1) {
        if (t < off) s_red[t] += s_red[t + off];
        __syncthreads();
    }
    float r = s_red[0]; __syncthreads();
    return r;
}
__device__ inline float block_max256(float v, float* s_red) {
    int t = threadIdx.x;
    s_red[t] = v; __syncthreads();
    for (int off = 128; off > 0; off >>= 1) {
        if (t < off) s_red[t] = fmaxf(s_red[t], s_red[t + off]);
        __syncthreads();
    }
    float r = s_red[0]; __syncthreads();
    return r;
}
__device__ inline unsigned int fenc(float f) {
    unsigned int b = __float_as_uint(f);
    return (b & 0x80000000u) ? ~b : (b | 0x80000000u);
}
__device__ inline float fdec(unsigned int u) {
    return (u & 0x80000000u) ? __uint_as_float(u ^ 0x80000000u) : __uint_as_float(~u);
}

// ---------------- SGEMM: C[M,N] = A[M,K] @ W[K,N] + bias[N] ----------------
__global__ __launch_bounds__(256)
void sgemm_bias(const float* __restrict__ A, const float* __restrict__ W,
                const float* __restrict__ bias, float* __restrict__ C) {
    const int N = DD, K = DD;
    __shared__ float As[16][65];
    __shared__ float Bs[16][65];
    int t = threadIdx.x;
    int n0 = blockIdx.x * 64, m0 = blockIdx.y * 64;
    int ty = t >> 4, tx = t & 15;
    float acc[4][4] = {};
    for (int k0 = 0; k0 < K; k0 += 16) {
#pragma unroll
        for (int i = 0; i < 4; i++) {
            int e = t + i * 256;
            int mm = e >> 4, kk = e & 15;
            As[kk][mm] = A[(size_t)(m0 + mm) * K + k0 + kk];
        }
#pragma unroll
        for (int i = 0; i < 4; i++) {
            int e = t + i * 256;
            int kk = e >> 6, nn = e & 63;
            Bs[kk][nn] = W[(size_t)(k0 + kk) * N + n0 + nn];
        }
        __syncthreads();
#pragma unroll
        for (int kk = 0; kk < 16; kk++) {
            float a[4], b[4];
#pragma unroll
            for (int i = 0; i < 4; i++) a[i] = As[kk][ty + 16 * i];
#pragma unroll
            for (int j = 0; j < 4; j++) b[j] = Bs[kk][tx + 16 * j];
#pragma unroll
            for (int i = 0; i < 4; i++)
#pragma unroll
                for (int j = 0; j < 4; j++) acc[i][j] += a[i] * b[j];
        }
        __syncthreads();
    }
#pragma unroll
    for (int i = 0; i < 4; i++) {
        int m = m0 + ty + 16 * i;
#pragma unroll
        for (int j = 0; j < 4; j++) {
            int n = n0 + tx + 16 * j;
            C[(size_t)m * N + n] = acc[i][j] + bias[n];
        }
    }
}

// ---------------- alv = (A @ Wp + bias) transposed to (B,H,L) ----------------
__global__ __launch_bounds__(256)
void alv_gemm(const float* __restrict__ A, const float* __restrict__ Wp,
              const float* __restrict__ bias, float* __restrict__ alv) {
    __shared__ float As[16][65];
    __shared__ float Ws[64][17];
    int t = threadIdx.x;
    int m0 = blockIdx.x * 16;
    int r = t >> 4, hh = t & 15;
    float acc = 0.f;
    for (int kt = 0; kt < 16; kt++) {
        __syncthreads();
#pragma unroll
        for (int i = 0; i < 4; i++) {
            int e = t + i * 256;
            int rr = e >> 6, kk = e & 63;
            As[rr][kk] = A[(size_t)(m0 + rr) * DD + kt * 64 + kk];
        }
#pragma unroll
        for (int i = 0; i < 4; i++) {
            int e = t + i * 256;
            int kk = e >> 4, h2 = e & 15;
            Ws[kk][h2] = Wp[(size_t)(kt * 64 + kk) * HH + h2];
        }
        __syncthreads();
#pragma unroll
        for (int kk = 0; kk < 64; kk++) acc += As[r][kk] * Ws[kk][hh];
    }
    int m = m0 + r;
    int b = m >> 9, l = m & 511;
    alv[(size_t)(b * HH + hh) * LL + l] = acc + bias[hh];
}

// ---------------- clustering ----------------
__global__ __launch_bounds__(256)
void cluster_kernel(const float* __restrict__ zsrc, const float* __restrict__ alv,
                    const float* __restrict__ mu, const float* __restrict__ logvar,
                    const float* __restrict__ logprior,
                    float* __restrict__ cp_out, float* __restrict__ lpdf_out,
                    unsigned int* __restrict__ maxenc, float* __restrict__ kl_out,
                    int isHead) {
    __shared__ float s_mu[CC * DK], s_iv[CC * DK], s_lv[CC * DK];
    __shared__ float s_slv[CC], s_siv[CC], s_lp[CC];
    __shared__ float s_red[256];
    int t = threadIdx.x;
    int tile = blockIdx.x & 1;
    int bh = blockIdx.x >> 1;
    int h = bh & (HH - 1), b = bh >> 4;
    int hm = isHead ? 0 : h;

    {
        float m = mu[hm * CC * DK + t];
        float lv = logvar[hm * CC * DK + t];
        s_mu[t] = m; s_lv[t] = lv; s_iv[t] = expf(-lv);
    }
    __syncthreads();
    if (t < CC) {
        float slv = 0.f, siv = 0.f;
        for (int d = 0; d < DK; d++) { slv += s_lv[t * DK + d]; siv += s_iv[t * DK + d]; }
        s_slv[t] = slv; s_siv[t] = siv;
    }
    if (t == CC) {
        float x[CC];
        float m = -1e30f;
        for (int c = 0; c < CC; c++) { x[c] = logprior[hm * CC + c]; m = fmaxf(m, x[c]); }
        float se = 0.f;
        for (int c = 0; c < CC; c++) se += expf(x[c] - m);
        float lse = m + logf(se);
        for (int c = 0; c < CC; c++) s_lp[c] = x[c] - lse;
    }
    __syncthreads();

    int l = tile * 256 + t;
    const float* zp = zsrc + ((size_t)(b * LL + l)) * DD + h * DK;
    float acc[CC] = {0.f, 0.f, 0.f, 0.f};
    for (int d = 0; d < DK; d += 4) {
        float4 z4 = *(const float4*)(zp + d);
#pragma unroll
        for (int c = 0; c < CC; c++) {
            float d0 = z4.x - s_mu[c * DK + d];     acc[c] += d0 * d0 * s_iv[c * DK + d];
            float d1 = z4.y - s_mu[c * DK + d + 1]; acc[c] += d1 * d1 * s_iv[c * DK + d + 1];
            float d2 = z4.z - s_mu[c * DK + d + 2]; acc[c] += d2 * d2 * s_iv[c * DK + d + 2];
            float d3 = z4.w - s_mu[c * DK + d + 3]; acc[c] += d3 * d3 * s_iv[c * DK + d + 3];
        }
    }
    float lpdf[CC];
#pragma unroll
    for (int c = 0; c < CC; c++)
        lpdf[c] = -0.5f * acc[c] - 0.5f * s_slv[c] - NEG_DPI + s_lp[c];
    float m = fmaxf(fmaxf(lpdf[0], lpdf[1]), fmaxf(lpdf[2], lpdf[3]));
    float se = 0.f;
#pragma unroll
    for (int c = 0; c < CC; c++) se += expf(lpdf[c] - m);
    float lse = m + logf(se);
    float lprob[CC], cpv[CC];
    size_t idx = ((size_t)(bh * LL + l)) * CC;
#pragma unroll
    for (int c = 0; c < CC; c++) {
        lprob[c] = lpdf[c] - lse;
        cpv[c] = expf(lprob[c]);
        cp_out[idx + c] = cpv[c];
    }
    if (isHead) {
#pragma unroll
        for (int c = 0; c < CC; c++) lpdf_out[idx + c] = lpdf[c];
    }
    float alvv = alv[(size_t)bh * LL + l];
    float avar = expf(alvv);
    float t1 = 0.f, t2 = 0.f;
#pragma unroll
    for (int c = 0; c < CC; c++) {
        t1 += expf(s_lp[c]) * (s_lp[c] - lprob[c]);
        t2 += cpv[c] * (acc[c] + avar * s_siv[c] + s_slv[c]);
    }
    float klv = t1 + 0.5f * t2 - 0.5f * (float)DK * (1.0f + alvv);
    float tot = block_sum256(klv, s_red);
    if (t == 0) atomicAdd(kl_out + b, tot * (1.0f / (HH * LL)));
    if (isHead) {
        float mt = block_max256(m, s_red);
        if (t == 0) atomicMax(maxenc, fenc(mt));
    }
}

// ---------------- pair stats: div loss (+ head: diag log_softmax(aff)) ----------------
__global__ __launch_bounds__(256)
void pairstats_kernel(const float* __restrict__ cp, float* __restrict__ div_out,
                      float* __restrict__ mi_out, int isHead) {
    __shared__ float s_cp[LL * CC];
    __shared__ float s_red[256];
    int t = threadIdx.x;
    int bh = blockIdx.x;
    int b = bh >> 4;
    const float* base = cp + (size_t)bh * LL * CC;
#pragma unroll
    for (int i = 0; i < 8; i++) s_cp[t + i * 256] = base[t + i * 256];
    __syncthreads();
    float divacc = 0.f, diagacc = 0.f;
    for (int qi = 0; qi < 2; qi++) {
        int q = t + qi * 256;
        float c0 = s_cp[q * 4 + 0], c1 = s_cp[q * 4 + 1], c2 = s_cp[q * 4 + 2], c3 = s_cp[q * 4 + 3];
        float m = -1e30f, s = 0.f, selfdot = 0.f;
        for (int k = 0; k < LL; k++) {
            float dot = c0 * s_cp[k * 4 + 0] + c1 * s_cp[k * 4 + 1] + c2 * s_cp[k * 4 + 2] + c3 * s_cp[k * 4 + 3];
            float del = (k == q) ? 1.f : 0.f;
            float dd = dot - del;
            divacc += dd * dd * (del * 1.25f + (1.f - del) * 0.75f);
            if (isHead) {
                if (dot > m) { s = s * expf(m - dot) + 1.f; m = dot; }
                else         { s += expf(dot - m); }
                if (k == q) selfdot = dot;
            }
        }
        if (isHead) diagacc += selfdot - (m + logf(s));
    }
    float dtot = block_sum256(divacc, s_red);
    if (t == 0) atomicAdd(div_out + b, dtot * (1.0f / ((float)HH * LL * LL)));
    if (isHead) {
        float gtot = block_sum256(diagacc, s_red);
        if (t == 0) atomicAdd(mi_out + b, -gtot * (1.0f / (HH * LL)));
    }
}

// ---------------- attention v2: one (b,h,16-row q-tile) per block ----------------
// grid: (32 qtiles, hpg heads, 8 batches); writes per-head probs to attn_h scratch.
#define QT2 16
__global__ __launch_bounds__(256)
void attn2_kernel(const float* __restrict__ qb, const float* __restrict__ kb,
                  const float* __restrict__ vb, const float* __restrict__ cpq,
                  float* __restrict__ ctxf, float* __restrict__ attn_h,
                  int h0, int hpg) {
    __shared__ float s_q[QT2 * 64];       // 4 KiB
    __shared__ float s_k[64 * 65];        // 16.25 KiB (k/v tile, +1 pad)
    __shared__ float s_sc[QT2 * 520];     // 32.5 KiB score rows
    __shared__ float s_cp[LL * CC];       // 8 KiB
    __shared__ float s_inv[QT2];
    int t = threadIdx.x;
    int qt = blockIdx.x;
    int hl = blockIdx.y;
    int b  = blockIdx.z;
    int h  = h0 + hl;
    int q0 = qt * QT2;

    // stage q tile (16x64) + cp rows (512x4), vectorized
    {
        int r = t >> 4, d4 = (t & 15) * 4;
        float4 v = *(const float4*)&qb[((size_t)(b * LL + q0 + r)) * DD + h * DK + d4];
        *(float4*)&s_q[r * 64 + d4] = v;
        const float* cpb = cpq + (size_t)(b * HH + h) * LL * CC;
#pragma unroll
        for (int i = 0; i < 2; i++) {
            int e = (t + i * 256) * 4;
            *(float4*)&s_cp[e] = *(const float4*)&cpb[e];
        }
    }

    int col  = t & 63;
    int rgrp = t >> 6;   // wave-uniform

    // ---- scores: 8 k-tiles of 64 ----
    for (int kt = 0; kt < 8; kt++) {
        __syncthreads();
#pragma unroll
        for (int i = 0; i < 4; i++) {
            int e = t + i * 256;              // float4 unit
            int kk = e >> 4, d4 = (e & 15) * 4;
            float4 v = *(const float4*)&kb[((size_t)(b * LL + kt * 64 + kk)) * DD + h * DK + d4];
            s_k[kk * 65 + d4 + 0] = v.x; s_k[kk * 65 + d4 + 1] = v.y;
            s_k[kk * 65 + d4 + 2] = v.z; s_k[kk * 65 + d4 + 3] = v.w;
        }
        __syncthreads();
        float a0 = 0.f, a1 = 0.f, a2 = 0.f, a3 = 0.f;
#pragma unroll
        for (int d4 = 0; d4 < 64; d4 += 4) {
            float k0 = s_k[col * 65 + d4 + 0];
            float k1 = s_k[col * 65 + d4 + 1];
            float k2 = s_k[col * 65 + d4 + 2];
            float k3 = s_k[col * 65 + d4 + 3];
            float4 q0v = *(float4*)&s_q[(rgrp + 0)  * 64 + d4];
            float4 q1v = *(float4*)&s_q[(rgrp + 4)  * 64 + d4];
            float4 q2v = *(float4*)&s_q[(rgrp + 8)  * 64 + d4];
            float4 q3v = *(float4*)&s_q[(rgrp + 12) * 64 + d4];
            a0 += q0v.x * k0 + q0v.y * k1 + q0v.z * k2 + q0v.w * k3;
            a1 += q1v.x * k0 + q1v.y * k1 + q1v.z * k2 + q1v.w * k3;
            a2 += q2v.x * k0 + q2v.y * k1 + q2v.z * k2 + q2v.w * k3;
            a3 += q3v.x * k0 + q3v.y * k1 + q3v.z * k2 + q3v.w * k3;
        }
        int kc = kt * 64 + col;
        s_sc[(rgrp + 0)  * 520 + kc] = a0 * 0.125f;
        s_sc[(rgrp + 4)  * 520 + kc] = a1 * 0.125f;
        s_sc[(rgrp + 8)  * 520 + kc] = a2 * 0.125f;
        s_sc[(rgrp + 12) * 520 + kc] = a3 * 0.125f;
    }
    __syncthreads();

    // ---- softmax + mask + renorm: 16 lanes per row ----
    {
        int r = t >> 4, lane = t & 15;
        float m = -1e30f;
        for (int k = lane; k < LL; k += 16) m = fmaxf(m, s_sc[r * 520 + k]);
#pragma unroll
        for (int off = 8; off > 0; off >>= 1) m = fmaxf(m, __shfl_xor(m, off, 16));
        float4 cq = *(float4*)&s_cp[(q0 + r) * 4];
        float Z = 0.f, S = 0.f;
        for (int k = lane; k < LL; k += 16) {
            float e = expf(s_sc[r * 520 + k] - m);
            float4 ck = *(float4*)&s_cp[k * 4];
            float mask = cq.x * ck.x + cq.y * ck.y + cq.z * ck.z + cq.w * ck.w;
            float a = e * mask;
            Z += e; S += a;
            s_sc[r * 520 + k] = a;
        }
#pragma unroll
        for (int off = 8; off > 0; off >>= 1) {
            Z += __shfl_xor(Z, off, 16);
            S += __shfl_xor(S, off, 16);
        }
        if (lane == 0) s_inv[r] = 1.f / (S + 1e-6f * Z);
    }
    __syncthreads();

    // ---- normalize in place + write per-head probs to scratch (coalesced) ----
    {
        float* dst = attn_h + ((size_t)(b * hpg + hl) * LL + q0) * LL;
#pragma unroll
        for (int i = 0; i < 8; i++) {
            int e = t + i * 256;            // float4 unit, 2048 total
            int r2 = e >> 7, k4 = (e & 127) * 4;
            float4 v = *(float4*)&s_sc[r2 * 520 + k4];
            float inv = s_inv[r2];
            v.x *= inv; v.y *= inv; v.z *= inv; v.w *= inv;
            *(float4*)&s_sc[r2 * 520 + k4] = v;
            *(float4*)&dst[(size_t)r2 * LL + k4] = v;
        }
    }

    // ---- ctx = attn @ V ----
    int d = t & 63;
    float c0 = 0.f, c1 = 0.f, c2 = 0.f, c3 = 0.f;
    for (int kt = 0; kt < 8; kt++) {
        __syncthreads();
#pragma unroll
        for (int i = 0; i < 4; i++) {
            int e = t + i * 256;
            int kk = e >> 4, d4 = (e & 15) * 4;
            float4 v = *(const float4*)&vb[((size_t)(b * LL + kt * 64 + kk)) * DD + h * DK + d4];
            s_k[kk * 65 + d4 + 0] = v.x; s_k[kk * 65 + d4 + 1] = v.y;
            s_k[kk * 65 + d4 + 2] = v.z; s_k[kk * 65 + d4 + 3] = v.w;
        }
        __syncthreads();
#pragma unroll
        for (int kk4 = 0; kk4 < 64; kk4 += 4) {
            float v0 = s_k[(kk4 + 0) * 65 + d];
            float v1 = s_k[(kk4 + 1) * 65 + d];
            float v2 = s_k[(kk4 + 2) * 65 + d];
            float v3 = s_k[(kk4 + 3) * 65 + d];
            int kc = kt * 64 + kk4;
            float4 p0 = *(float4*)&s_sc[(rgrp + 0)  * 520 + kc];
            float4 p1 = *(float4*)&s_sc[(rgrp + 4)  * 520 + kc];
            float4 p2 = *(float4*)&s_sc[(rgrp + 8)  * 520 + kc];
            float4 p3 = *(float4*)&s_sc[(rgrp + 12) * 520 + kc];
            c0 += p0.x * v0 + p0.y * v1 + p0.z * v2 + p0.w * v3;
            c1 += p1.x * v0 + p1.y * v1 + p1.z * v2 + p1.w * v3;
            c2 += p2.x * v0 + p2.y * v1 + p2.z * v2 + p2.w * v3;
            c3 += p3.x * v0 + p3.y * v1 + p3.z * v2 + p3.w * v3;
        }
    }
    ctxf[((size_t)(b * LL + q0 + rgrp + 0))  * DD + h * DK + d] = c0;
    ctxf[((size_t)(b * LL + q0 + rgrp + 4))  * DD + h * DK + d] = c1;
    ctxf[((size_t)(b * LL + q0 + rgrp + 8))  * DD + h * DK + d] = c2;
    ctxf[((size_t)(b * LL + q0 + rgrp + 12)) * DD + h * DK + d] = c3;
}

// ---------------- reduce per-head probs into attn mean ----------------
__global__ __launch_bounds__(256)
void attn_reduce(const float* __restrict__ attn_h, float* __restrict__ attn_out,
                 int hpg, int accumulate) {
    int e = blockIdx.x * 256 + threadIdx.x;  // float4 unit; total 8*65536
    int b = e >> 16;
    int rem = e & 65535;
    float4 s = {0.f, 0.f, 0.f, 0.f};
    for (int hl = 0; hl < hpg; hl++) {
        float4 v = ((const float4*)attn_h)[(((size_t)(b * hpg + hl)) << 16) + rem];
        s.x += v.x; s.y += v.y; s.z += v.z; s.w += v.w;
    }
    float4* o = (float4*)attn_out + (((size_t)b) << 16) + rem;
    const float sc = 1.0f / (float)HH;
    float4 prev = {0.f, 0.f, 0.f, 0.f};
    if (accumulate) prev = *o;
    prev.x += s.x * sc; prev.y += s.y * sc; prev.z += s.z * sc; prev.w += s.w * sc;
    *o = prev;
}

// ---------------- MI: pdf + wsum ----------------
__global__ __launch_bounds__(256)
void wsum_kernel(const float* __restrict__ lpdf, const float* __restrict__ cp,
                 const unsigned int* __restrict__ maxenc,
                 float* __restrict__ pdf_out, float* __restrict__ wsum_out) {
    __shared__ float s_red[256];
    int t = threadIdx.x;
    int bh = blockIdx.x;
    float M = fdec(*maxenc);
    float a[CC] = {0.f, 0.f, 0.f, 0.f};
    for (int li = 0; li < 2; li++) {
        int l = t + li * 256;
        size_t idx = ((size_t)bh * LL + l) * CC;
        float p0 = expf(lpdf[idx + 0] - M);
        float p1 = expf(lpdf[idx + 1] - M);
        float p2 = expf(lpdf[idx + 2] - M);
        float p3 = expf(lpdf[idx + 3] - M);
        float pd = p0 + p1 + p2 + p3;
        pdf_out[(size_t)bh * LL + l] = pd;
        a[0] += cp[idx + 0] * pd; a[1] += cp[idx + 1] * pd;
        a[2] += cp[idx + 2] * pd; a[3] += cp[idx + 3] * pd;
    }
#pragma unroll
    for (int c = 0; c < CC; c++) {
        float tot = block_sum256(a[c], s_red);
        if (t == 0) wsum_out[bh * CC + c] = tot;
    }
}

// ---------------- MI: pairwise head overlap ----------------
__global__ __launch_bounds__(256)
void mi_kernel(const float* __restrict__ cp, const float* __restrict__ pdf,
               const float* __restrict__ wsum, float* __restrict__ mi_out) {
    __shared__ float s_q[HH * CC];
    __shared__ float s_c[HH * CC];
    __shared__ float s_red[256];
    int t = threadIdx.x;
    int b = blockIdx.x >> 9;
    int l = blockIdx.x & 511;
    if (t < HH * CC) {
        int i = t >> 2, c = t & 3;
        float cpv = cp[((size_t)(b * HH + i) * LL + l) * CC + c];
        s_c[t] = cpv;
        float w = cpv * pdf[(size_t)(b * HH + i) * LL + l];
        float ws = wsum[(b * HH + i) * CC + c];
        s_q[t] = w / fmaxf(ws, 1e-6f);
    }
    __syncthreads();
    int i = t >> 4, j = t & 15;
    float sdot = 0.f;
#pragma unroll
    for (int c = 0; c < CC; c++) sdot += s_q[i * 4 + c] * s_c[j * 4 + c];
    float mi_p = fminf(sdot, 1.f);
    float val = (i != j) ? logf(1.f - mi_p + 1e-6f) : 0.f;
    float tot = block_sum256(val, s_red);
    if (t == 0) atomicAdd(mi_out + b, -10.f * tot * (1.0f / ((float)LL * HH * HH)));
}

// ---------------- launcher ----------------
extern "C" void kernel_launch(void* const* d_in, const int* in_sizes, int n_in,
                              void* d_out, int out_size, void* d_ws, size_t ws_size,
                              hipStream_t stream) {
    (void)in_sizes; (void)n_in; (void)out_size;
    const float* query  = (const float*)d_in[0];
    const float* key    = (const float*)d_in[1];
    const float* value  = (const float*)d_in[2];
    const float* Wq     = (const float*)d_in[3];
    const float* bq     = (const float*)d_in[4];
    const float* Wk     = (const float*)d_in[5];
    const float* bk     = (const float*)d_in[6];
    const float* Wv     = (const float*)d_in[7];
    const float* bv     = (const float*)d_in[8];
    const float* Wo     = (const float*)d_in[9];
    const float* bo     = (const float*)d_in[10];
    const float* Wsem   = (const float*)d_in[11];
    const float* bsem   = (const float*)d_in[12];
    const float* Whead  = (const float*)d_in[13];
    const float* bhead  = (const float*)d_in[14];
    const float* tokmu  = (const float*)d_in[15];
    const float* toklv  = (const float*)d_in[16];
    const float* toklp  = (const float*)d_in[17];
    const float* headmu = (const float*)d_in[18];
    const float* headlv = (const float*)d_in[19];
    const float* headlp = (const float*)d_in[20];

    float* ws   = (float*)d_ws;
    const size_t NBLD = (size_t)BB * LL * DD;      // 4194304
    float* q    = ws;
    float* k    = ws + NBLD;
    float* v    = ws + 2 * NBLD;
    float* ctxf = ws + 3 * NBLD;
    float* alvq = ws + 4 * NBLD;
    float* alvh = alvq + (size_t)BB * HH * LL;
    float* cpq  = alvh + (size_t)BB * HH * LL;
    float* cph  = cpq + (size_t)BB * HH * LL * CC;
    float* lpdfh= cph + (size_t)BB * HH * LL * CC;
    float* pdfb = lpdfh + (size_t)BB * HH * LL * CC;
    float* wsumb= pdfb + (size_t)BB * HH * LL;
    unsigned int* maxenc = (unsigned int*)(wsumb + (size_t)BB * HH * CC);
    float* attn_h = (float*)(maxenc + 4);   // 16B-aligned tail scratch

    size_t base_bytes = (size_t)((char*)attn_h - (char*)d_ws);
    int hpg = 1;
    {
        int cands[5] = {16, 8, 4, 2, 1};
        for (int i = 0; i < 5; i++) {
            size_t need = base_bytes + (size_t)BB * cands[i] * LL * LL * sizeof(float);
            if (need <= ws_size) { hpg = cands[i]; break; }
        }
    }

    float* out      = (float*)d_out;
    float* attn_out = out + NBLD;
    float* kl_out   = attn_out + (size_t)BB * LL * LL;
    float* div_out  = kl_out + BB;
    float* mi_out   = div_out + BB;

    hipMemsetAsync(kl_out, 0, 3 * BB * sizeof(float), stream);
    hipMemsetAsync(maxenc, 0, sizeof(unsigned int), stream);

    dim3 gg(DD / 64, BB * LL / 64);
    sgemm_bias<<<gg, 256, 0, stream>>>(query, Wq, bq, q);
    sgemm_bias<<<gg, 256, 0, stream>>>(key,   Wk, bk, k);
    sgemm_bias<<<gg, 256, 0, stream>>>(value, Wv, bv, v);
    alv_gemm<<<BB * LL / 16, 256, 0, stream>>>(q, Wsem, bsem, alvq);
    cluster_kernel<<<BB * HH * 2, 256, 0, stream>>>(q, alvq, tokmu, toklv, toklp,
                                                    cpq, nullptr, nullptr, kl_out, 0);
    pairstats_kernel<<<BB * HH, 256, 0, stream>>>(cpq, div_out, nullptr, 0);

    for (int h0 = 0; h0 < HH; h0 += hpg) {
        attn2_kernel<<<dim3(LL / QT2, hpg, BB), 256, 0, stream>>>(
            q, k, v, cpq, ctxf, attn_h, h0, hpg);
        attn_reduce<<<BB * LL * LL / 4 / 256, 256, 0, stream>>>(
            attn_h, attn_out, hpg, h0 > 0 ? 1 : 0);
    }

    alv_gemm<<<BB * LL / 16, 256, 0, stream>>>(ctxf, Whead, bhead, alvh);
    cluster_kernel<<<BB * HH * 2, 256, 0, stream>>>(ctxf, alvh, headmu, headlv, headlp,
                                                    cph, lpdfh, maxenc, kl_out, 1);
    pairstats_kernel<<<BB * HH, 256, 0, stream>>>(cph, div_out, mi_out, 1);
    wsum_kernel<<<BB * HH, 256, 0, stream>>>(lpdfh, cph, maxenc, pdfb, wsumb);
    mi_kernel<<<BB * LL, 256, 0, stream>>>(cph, pdfb, wsumb, mi_out);
    sgemm_bias<<<gg, 256, 0, stream>>>(ctxf, Wo, bo, out);
}

// Round 3
// 1241.184 us; speedup vs baseline: 2.1858x; 1.2806x over previous
//
#include <hip/hip_runtime.h>
#include <math.h>

// Problem constants: B=8, L=512, D=1024, H=16, C=4, Dk=64
#define BB 8
#define LL 512
#define DD 1024
#define HH 16
#define CC 4
#define DK 64
#define NEG_DPI 201.06192982974676f   // 64 * pi

typedef __attribute__((ext_vector_type(8))) short short8;     // MFMA A/B frag (8 bf16)
typedef __attribute__((ext_vector_type(4))) float floatx4;    // MFMA C/D frag
typedef __attribute__((ext_vector_type(8))) unsigned short u16x8;
typedef __attribute__((ext_vector_type(4))) unsigned short u16x4;

// ---------------- helpers ----------------
__device__ inline float block_sum256(float v, float* s_red) {
    int t = threadIdx.x;
    s_red[t] = v; __syncthreads();
    for (int off = 128; off > 0; off >>= 1) {
        if (t < off) s_red[t] += s_red[t + off];
        __syncthreads();
    }
    float r = s_red[0]; __syncthreads();
    return r;
}
__device__ inline float block_max256(float v, float* s_red) {
    int t = threadIdx.x;
    s_red[t] = v; __syncthreads();
    for (int off = 128; off > 0; off >>= 1) {
        if (t < off) s_red[t] = fmaxf(s_red[t], s_red[t + off]);
        __syncthreads();
    }
    float r = s_red[0]; __syncthreads();
    return r;
}
__device__ inline unsigned int fenc(float f) {
    unsigned int b = __float_as_uint(f);
    return (b & 0x80000000u) ? ~b : (b | 0x80000000u);
}
__device__ inline float fdec(unsigned int u) {
    return (u & 0x80000000u) ? __uint_as_float(u ^ 0x80000000u) : __uint_as_float(~u);
}
__device__ inline unsigned short f2bf(float x) {   // RNE fp32 -> bf16
    unsigned int u = __float_as_uint(x);
    return (unsigned short)((u + 0x7FFFu + ((u >> 16) & 1u)) >> 16);
}

// ---------------- fp32 -> bf16 hi/lo split (elementwise) ----------------
__global__ __launch_bounds__(256)
void convert_hilo(const float* __restrict__ x, unsigned short* __restrict__ hh,
                  unsigned short* __restrict__ ll) {
    int i = blockIdx.x * 256 + threadIdx.x;     // float4 unit
    float4 v = ((const float4*)x)[i];
    u16x4 h, l;
    float c[4] = {v.x, v.y, v.z, v.w};
#pragma unroll
    for (int j = 0; j < 4; j++) {
        unsigned short hb = f2bf(c[j]);
        float hf = __uint_as_float((unsigned int)hb << 16);
        h[j] = hb;
        l[j] = f2bf(c[j] - hf);
    }
    ((u16x4*)hh)[i] = h;
    ((u16x4*)ll)[i] = l;
}

// ---------------- weight transpose + hi/lo convert: W[K][N] -> Wt[N][K] ----------------
__global__ __launch_bounds__(256)
void wconv_kernel(const float* __restrict__ W, unsigned short* __restrict__ Th,
                  unsigned short* __restrict__ Tl) {
    __shared__ float tile[64][65];
    int t = threadIdx.x;
    int n0 = blockIdx.x * 64, k0 = blockIdx.y * 64;
    int r = t >> 4, c4 = (t & 15) * 4;
#pragma unroll
    for (int rr = 0; rr < 64; rr += 16) {
        float4 v = *(const float4*)&W[(size_t)(k0 + r + rr) * DD + n0 + c4];
        tile[r + rr][c4 + 0] = v.x; tile[r + rr][c4 + 1] = v.y;
        tile[r + rr][c4 + 2] = v.z; tile[r + rr][c4 + 3] = v.w;
    }
    __syncthreads();
    int rn = t >> 2, kg = (t & 3) * 16;
    u16x8 oh[2], ol[2];
#pragma unroll
    for (int j = 0; j < 16; j++) {
        float x = tile[kg + j][rn];
        unsigned short hb = f2bf(x);
        float hf = __uint_as_float((unsigned int)hb << 16);
        oh[j >> 3][j & 7] = hb;
        ol[j >> 3][j & 7] = f2bf(x - hf);
    }
    size_t o = (size_t)(n0 + rn) * DD + k0 + kg;
    *(u16x8*)&Th[o] = oh[0]; *(u16x8*)&Th[o + 8] = oh[1];
    *(u16x8*)&Tl[o] = ol[0]; *(u16x8*)&Tl[o + 8] = ol[1];
}

// ---------------- split-bf16 MFMA GEMM: C[M][1024] = A[M][1024] @ Wt^T + bias ----------------
// A given as hi/lo bf16 [M][K]; W given as hi/lo bf16 TRANSPOSED [N][K].
// 128x128 tile, BK=32, 4 waves each computing 64x64 via 4x4 grid of 16x16x32 MFMA.
// 3-pass: Ah*Bh + Ah*Bl + Al*Bh  (fp32-accurate to ~1e-5 rel).
__global__ __launch_bounds__(256)
void mfma_gemm_bias(const unsigned short* __restrict__ Ah, const unsigned short* __restrict__ Al,
                    const unsigned short* __restrict__ Bh, const unsigned short* __restrict__ Bl,
                    const float* __restrict__ bias, float* __restrict__ C) {
    __shared__ unsigned short sAh[128 * 32];
    __shared__ unsigned short sAl[128 * 32];
    __shared__ unsigned short sBh[128 * 32];
    __shared__ unsigned short sBl[128 * 32];
    int t = threadIdx.x;
    int n0 = blockIdx.x * 128, m0 = blockIdx.y * 128;
    int lane = t & 63, w = t >> 6;
    int wm = w >> 1, wn = w & 1;
    int lm = lane & 15, quad = lane >> 4;
    int srow = t >> 1, sk = (t & 1) * 16;

    const unsigned short* gAh = Ah + (size_t)(m0 + srow) * DD + sk;
    const unsigned short* gAl = Al + (size_t)(m0 + srow) * DD + sk;
    const unsigned short* gBh = Bh + (size_t)(n0 + srow) * DD + sk;
    const unsigned short* gBl = Bl + (size_t)(n0 + srow) * DD + sk;
    unsigned short* wAh = &sAh[srow * 32 + sk];
    unsigned short* wAl = &sAl[srow * 32 + sk];
    unsigned short* wBh = &sBh[srow * 32 + sk];
    unsigned short* wBl = &sBl[srow * 32 + sk];

    floatx4 acc[4][4] = {};

    for (int kt = 0; kt < 32; kt++) {
        int kb = kt * 32;
        u16x8 a0 = *(const u16x8*)(gAh + kb);
        u16x8 a1 = *(const u16x8*)(gAh + kb + 8);
        u16x8 a2 = *(const u16x8*)(gAl + kb);
        u16x8 a3 = *(const u16x8*)(gAl + kb + 8);
        u16x8 b0 = *(const u16x8*)(gBh + kb);
        u16x8 b1 = *(const u16x8*)(gBh + kb + 8);
        u16x8 b2 = *(const u16x8*)(gBl + kb);
        u16x8 b3 = *(const u16x8*)(gBl + kb + 8);
        __syncthreads();
        *(u16x8*)(wAh) = a0; *(u16x8*)(wAh + 8) = a1;
        *(u16x8*)(wAl) = a2; *(u16x8*)(wAl + 8) = a3;
        *(u16x8*)(wBh) = b0; *(u16x8*)(wBh + 8) = b1;
        *(u16x8*)(wBl) = b2; *(u16x8*)(wBl + 8) = b3;
        __syncthreads();

        short8 bh[4], bl[4];
#pragma unroll
        for (int j = 0; j < 4; j++) {
            int nb = (wn * 64 + j * 16 + lm) * 32 + quad * 8;
            bh[j] = *(const short8*)&sBh[nb];
            bl[j] = *(const short8*)&sBl[nb];
        }
#pragma unroll
        for (int i = 0; i < 4; i++) {
            int ab = (wm * 64 + i * 16 + lm) * 32 + quad * 8;
            short8 ah = *(const short8*)&sAh[ab];
            short8 al = *(const short8*)&sAl[ab];
#pragma unroll
            for (int j = 0; j < 4; j++) {
                acc[i][j] = __builtin_amdgcn_mfma_f32_16x16x32_bf16(ah, bh[j], acc[i][j], 0, 0, 0);
                acc[i][j] = __builtin_amdgcn_mfma_f32_16x16x32_bf16(ah, bl[j], acc[i][j], 0, 0, 0);
                acc[i][j] = __builtin_amdgcn_mfma_f32_16x16x32_bf16(al, bh[j], acc[i][j], 0, 0, 0);
            }
        }
    }
#pragma unroll
    for (int i = 0; i < 4; i++) {
#pragma unroll
        for (int j = 0; j < 4; j++) {
            int n = n0 + wn * 64 + j * 16 + lm;
            float bv = bias[n];
#pragma unroll
            for (int r = 0; r < 4; r++) {
                int m = m0 + wm * 64 + i * 16 + quad * 4 + r;
                C[(size_t)m * DD + n] = acc[i][j][r] + bv;
            }
        }
    }
}

// ---------------- alv = (A @ Wp + bias) transposed to (B,H,L) ----------------
__global__ __launch_bounds__(256)
void alv_gemm(const float* __restrict__ A, const float* __restrict__ Wp,
              const float* __restrict__ bias, float* __restrict__ alv) {
    __shared__ float As[16][65];
    __shared__ float Ws[64][17];
    int t = threadIdx.x;
    int m0 = blockIdx.x * 16;
    int r = t >> 4, hh = t & 15;
    float acc = 0.f;
    for (int kt = 0; kt < 16; kt++) {
        __syncthreads();
#pragma unroll
        for (int i = 0; i < 4; i++) {
            int e = t + i * 256;
            int rr = e >> 6, kk = e & 63;
            As[rr][kk] = A[(size_t)(m0 + rr) * DD + kt * 64 + kk];
        }
#pragma unroll
        for (int i = 0; i < 4; i++) {
            int e = t + i * 256;
            int kk = e >> 4, h2 = e & 15;
            Ws[kk][h2] = Wp[(size_t)(kt * 64 + kk) * HH + h2];
        }
        __syncthreads();
#pragma unroll
        for (int kk = 0; kk < 64; kk++) acc += As[r][kk] * Ws[kk][hh];
    }
    int m = m0 + r;
    int b = m >> 9, l = m & 511;
    alv[(size_t)(b * HH + hh) * LL + l] = acc + bias[hh];
}

// ---------------- clustering ----------------
__global__ __launch_bounds__(256)
void cluster_kernel(const float* __restrict__ zsrc, const float* __restrict__ alv,
                    const float* __restrict__ mu, const float* __restrict__ logvar,
                    const float* __restrict__ logprior,
                    float* __restrict__ cp_out, float* __restrict__ lpdf_out,
                    unsigned int* __restrict__ maxenc, float* __restrict__ kl_out,
                    int isHead) {
    __shared__ float s_mu[CC * DK], s_iv[CC * DK], s_lv[CC * DK];
    __shared__ float s_slv[CC], s_siv[CC], s_lp[CC];
    __shared__ float s_red[256];
    int t = threadIdx.x;
    int tile = blockIdx.x & 1;
    int bh = blockIdx.x >> 1;
    int h = bh & (HH - 1), b = bh >> 4;
    int hm = isHead ? 0 : h;

    {
        float m = mu[hm * CC * DK + t];
        float lv = logvar[hm * CC * DK + t];
        s_mu[t] = m; s_lv[t] = lv; s_iv[t] = expf(-lv);
    }
    __syncthreads();
    if (t < CC) {
        float slv = 0.f, siv = 0.f;
        for (int d = 0; d < DK; d++) { slv += s_lv[t * DK + d]; siv += s_iv[t * DK + d]; }
        s_slv[t] = slv; s_siv[t] = siv;
    }
    if (t == CC) {
        float x[CC];
        float m = -1e30f;
        for (int c = 0; c < CC; c++) { x[c] = logprior[hm * CC + c]; m = fmaxf(m, x[c]); }
        float se = 0.f;
        for (int c = 0; c < CC; c++) se += expf(x[c] - m);
        float lse = m + logf(se);
        for (int c = 0; c < CC; c++) s_lp[c] = x[c] - lse;
    }
    __syncthreads();

    int l = tile * 256 + t;
    const float* zp = zsrc + ((size_t)(b * LL + l)) * DD + h * DK;
    float acc[CC] = {0.f, 0.f, 0.f, 0.f};
    for (int d = 0; d < DK; d += 4) {
        float4 z4 = *(const float4*)(zp + d);
#pragma unroll
        for (int c = 0; c < CC; c++) {
            float d0 = z4.x - s_mu[c * DK + d];     acc[c] += d0 * d0 * s_iv[c * DK + d];
            float d1 = z4.y - s_mu[c * DK + d + 1]; acc[c] += d1 * d1 * s_iv[c * DK + d + 1];
            float d2 = z4.z - s_mu[c * DK + d + 2]; acc[c] += d2 * d2 * s_iv[c * DK + d + 2];
            float d3 = z4.w - s_mu[c * DK + d + 3]; acc[c] += d3 * d3 * s_iv[c * DK + d + 3];
        }
    }
    float lpdf[CC];
#pragma unroll
    for (int c = 0; c < CC; c++)
        lpdf[c] = -0.5f * acc[c] - 0.5f * s_slv[c] - NEG_DPI + s_lp[c];
    float m = fmaxf(fmaxf(lpdf[0], lpdf[1]), fmaxf(lpdf[2], lpdf[3]));
    float se = 0.f;
#pragma unroll
    for (int c = 0; c < CC; c++) se += expf(lpdf[c] - m);
    float lse = m + logf(se);
    float lprob[CC], cpv[CC];
    size_t idx = ((size_t)(bh * LL + l)) * CC;
#pragma unroll
    for (int c = 0; c < CC; c++) {
        lprob[c] = lpdf[c] - lse;
        cpv[c] = expf(lprob[c]);
        cp_out[idx + c] = cpv[c];
    }
    if (isHead) {
#pragma unroll
        for (int c = 0; c < CC; c++) lpdf_out[idx + c] = lpdf[c];
    }
    float alvv = alv[(size_t)bh * LL + l];
    float avar = expf(alvv);
    float t1 = 0.f, t2 = 0.f;
#pragma unroll
    for (int c = 0; c < CC; c++) {
        t1 += expf(s_lp[c]) * (s_lp[c] - lprob[c]);
        t2 += cpv[c] * (acc[c] + avar * s_siv[c] + s_slv[c]);
    }
    float klv = t1 + 0.5f * t2 - 0.5f * (float)DK * (1.0f + alvv);
    float tot = block_sum256(klv, s_red);
    if (t == 0) atomicAdd(kl_out + b, tot * (1.0f / (HH * LL)));
    if (isHead) {
        float mt = block_max256(m, s_red);
        if (t == 0) atomicMax(maxenc, fenc(mt));
    }
}

// ---------------- pair stats: div loss (+ head: diag log_softmax(aff)) ----------------
__global__ __launch_bounds__(256)
void pairstats_kernel(const float* __restrict__ cp, float* __restrict__ div_out,
                      float* __restrict__ mi_out, int isHead) {
    __shared__ float s_cp[LL * CC];
    __shared__ float s_red[256];
    int t = threadIdx.x;
    int bh = blockIdx.x;
    int b = bh >> 4;
    const float* base = cp + (size_t)bh * LL * CC;
#pragma unroll
    for (int i = 0; i < 8; i++) s_cp[t + i * 256] = base[t + i * 256];
    __syncthreads();
    float divacc = 0.f, diagacc = 0.f;
    for (int qi = 0; qi < 2; qi++) {
        int q = t + qi * 256;
        float c0 = s_cp[q * 4 + 0], c1 = s_cp[q * 4 + 1], c2 = s_cp[q * 4 + 2], c3 = s_cp[q * 4 + 3];
        float m = -1e30f, s = 0.f, selfdot = 0.f;
        for (int k = 0; k < LL; k++) {
            float dot = c0 * s_cp[k * 4 + 0] + c1 * s_cp[k * 4 + 1] + c2 * s_cp[k * 4 + 2] + c3 * s_cp[k * 4 + 3];
            float del = (k == q) ? 1.f : 0.f;
            float dd = dot - del;
            divacc += dd * dd * (del * 1.25f + (1.f - del) * 0.75f);
            if (isHead) {
                if (dot > m) { s = s * expf(m - dot) + 1.f; m = dot; }
                else         { s += expf(dot - m); }
                if (k == q) selfdot = dot;
            }
        }
        if (isHead) diagacc += selfdot - (m + logf(s));
    }
    float dtot = block_sum256(divacc, s_red);
    if (t == 0) atomicAdd(div_out + b, dtot * (1.0f / ((float)HH * LL * LL)));
    if (isHead) {
        float gtot = block_sum256(diagacc, s_red);
        if (t == 0) atomicAdd(mi_out + b, -gtot * (1.0f / (HH * LL)));
    }
}

// ---------------- attention v2: one (b,h,16-row q-tile) per block ----------------
#define QT2 16
__global__ __launch_bounds__(256)
void attn2_kernel(const float* __restrict__ qb, const float* __restrict__ kb,
                  const float* __restrict__ vb, const float* __restrict__ cpq,
                  float* __restrict__ ctxf, float* __restrict__ attn_h,
                  int h0, int hpg) {
    __shared__ float s_q[QT2 * 64];
    __shared__ float s_k[64 * 65];
    __shared__ float s_sc[QT2 * 520];
    __shared__ float s_cp[LL * CC];
    __shared__ float s_inv[QT2];
    int t = threadIdx.x;
    int qt = blockIdx.x;
    int hl = blockIdx.y;
    int b  = blockIdx.z;
    int h  = h0 + hl;
    int q0 = qt * QT2;

    {
        int r = t >> 4, d4 = (t & 15) * 4;
        float4 v = *(const float4*)&qb[((size_t)(b * LL + q0 + r)) * DD + h * DK + d4];
        *(float4*)&s_q[r * 64 + d4] = v;
        const float* cpb = cpq + (size_t)(b * HH + h) * LL * CC;
#pragma unroll
        for (int i = 0; i < 2; i++) {
            int e = (t + i * 256) * 4;
            *(float4*)&s_cp[e] = *(const float4*)&cpb[e];
        }
    }

    int col  = t & 63;
    int rgrp = t >> 6;

    for (int kt = 0; kt < 8; kt++) {
        __syncthreads();
#pragma unroll
        for (int i = 0; i < 4; i++) {
            int e = t + i * 256;
            int kk = e >> 4, d4 = (e & 15) * 4;
            float4 v = *(const float4*)&kb[((size_t)(b * LL + kt * 64 + kk)) * DD + h * DK + d4];
            s_k[kk * 65 + d4 + 0] = v.x; s_k[kk * 65 + d4 + 1] = v.y;
            s_k[kk * 65 + d4 + 2] = v.z; s_k[kk * 65 + d4 + 3] = v.w;
        }
        __syncthreads();
        float a0 = 0.f, a1 = 0.f, a2 = 0.f, a3 = 0.f;
#pragma unroll
        for (int d4 = 0; d4 < 64; d4 += 4) {
            float k0 = s_k[col * 65 + d4 + 0];
            float k1 = s_k[col * 65 + d4 + 1];
            float k2 = s_k[col * 65 + d4 + 2];
            float k3 = s_k[col * 65 + d4 + 3];
            float4 q0v = *(float4*)&s_q[(rgrp + 0)  * 64 + d4];
            float4 q1v = *(float4*)&s_q[(rgrp + 4)  * 64 + d4];
            float4 q2v = *(float4*)&s_q[(rgrp + 8)  * 64 + d4];
            float4 q3v = *(float4*)&s_q[(rgrp + 12) * 64 + d4];
            a0 += q0v.x * k0 + q0v.y * k1 + q0v.z * k2 + q0v.w * k3;
            a1 += q1v.x * k0 + q1v.y * k1 + q1v.z * k2 + q1v.w * k3;
            a2 += q2v.x * k0 + q2v.y * k1 + q2v.z * k2 + q2v.w * k3;
            a3 += q3v.x * k0 + q3v.y * k1 + q3v.z * k2 + q3v.w * k3;
        }
        int kc = kt * 64 + col;
        s_sc[(rgrp + 0)  * 520 + kc] = a0 * 0.125f;
        s_sc[(rgrp + 4)  * 520 + kc] = a1 * 0.125f;
        s_sc[(rgrp + 8)  * 520 + kc] = a2 * 0.125f;
        s_sc[(rgrp + 12) * 520 + kc] = a3 * 0.125f;
    }
    __syncthreads();

    {
        int r = t >> 4, lane = t & 15;
        float m = -1e30f;
        for (int k = lane; k < LL; k += 16) m = fmaxf(m, s_sc[r * 520 + k]);
#pragma unroll
        for (int off = 8; off > 0; off >>= 1) m = fmaxf(m, __shfl_xor(m, off, 16));
        float4 cq = *(float4*)&s_cp[(q0 + r) * 4];
        float Z = 0.f, S = 0.f;
        for (int k = lane; k < LL; k += 16) {
            float e = expf(s_sc[r * 520 + k] - m);
            float4 ck = *(float4*)&s_cp[k * 4];
            float mask = cq.x * ck.x + cq.y * ck.y + cq.z * ck.z + cq.w * ck.w;
            float a = e * mask;
            Z += e; S += a;
            s_sc[r * 520 + k] = a;
        }
#pragma unroll
        for (int off = 8; off > 0; off >>= 1) {
            Z += __shfl_xor(Z, off, 16);
            S += __shfl_xor(S, off, 16);
        }
        if (lane == 0) s_inv[r] = 1.f / (S + 1e-6f * Z);
    }
    __syncthreads();

    {
        float* dst = attn_h + ((size_t)(b * hpg + hl) * LL + q0) * LL;
#pragma unroll
        for (int i = 0; i < 8; i++) {
            int e = t + i * 256;
            int r2 = e >> 7, k4 = (e & 127) * 4;
            float4 v = *(float4*)&s_sc[r2 * 520 + k4];
            float inv = s_inv[r2];
            v.x *= inv; v.y *= inv; v.z *= inv; v.w *= inv;
            *(float4*)&s_sc[r2 * 520 + k4] = v;
            *(float4*)&dst[(size_t)r2 * LL + k4] = v;
        }
    }

    int d = t & 63;
    float c0 = 0.f, c1 = 0.f, c2 = 0.f, c3 = 0.f;
    for (int kt = 0; kt < 8; kt++) {
        __syncthreads();
#pragma unroll
        for (int i = 0; i < 4; i++) {
            int e = t + i * 256;
            int kk = e >> 4, d4 = (e & 15) * 4;
            float4 v = *(const float4*)&vb[((size_t)(b * LL + kt * 64 + kk)) * DD + h * DK + d4];
            s_k[kk * 65 + d4 + 0] = v.x; s_k[kk * 65 + d4 + 1] = v.y;
            s_k[kk * 65 + d4 + 2] = v.z; s_k[kk * 65 + d4 + 3] = v.w;
        }
        __syncthreads();
#pragma unroll
        for (int kk4 = 0; kk4 < 64; kk4 += 4) {
            float v0 = s_k[(kk4 + 0) * 65 + d];
            float v1 = s_k[(kk4 + 1) * 65 + d];
            float v2 = s_k[(kk4 + 2) * 65 + d];
            float v3 = s_k[(kk4 + 3) * 65 + d];
            int kc = kt * 64 + kk4;
            float4 p0 = *(float4*)&s_sc[(rgrp + 0)  * 520 + kc];
            float4 p1 = *(float4*)&s_sc[(rgrp + 4)  * 520 + kc];
            float4 p2 = *(float4*)&s_sc[(rgrp + 8)  * 520 + kc];
            float4 p3 = *(float4*)&s_sc[(rgrp + 12) * 520 + kc];
            c0 += p0.x * v0 + p0.y * v1 + p0.z * v2 + p0.w * v3;
            c1 += p1.x * v0 + p1.y * v1 + p1.z * v2 + p1.w * v3;
            c2 += p2.x * v0 + p2.y * v1 + p2.z * v2 + p2.w * v3;
            c3 += p3.x * v0 + p3.y * v1 + p3.z * v2 + p3.w * v3;
        }
    }
    ctxf[((size_t)(b * LL + q0 + rgrp + 0))  * DD + h * DK + d] = c0;
    ctxf[((size_t)(b * LL + q0 + rgrp + 4))  * DD + h * DK + d] = c1;
    ctxf[((size_t)(b * LL + q0 + rgrp + 8))  * DD + h * DK + d] = c2;
    ctxf[((size_t)(b * LL + q0 + rgrp + 12)) * DD + h * DK + d] = c3;
}

// ---------------- reduce per-head probs into attn mean ----------------
__global__ __launch_bounds__(256)
void attn_reduce(const float* __restrict__ attn_h, float* __restrict__ attn_out,
                 int hpg, int accumulate) {
    int e = blockIdx.x * 256 + threadIdx.x;
    int b = e >> 16;
    int rem = e & 65535;
    float4 s = {0.f, 0.f, 0.f, 0.f};
    for (int hl = 0; hl < hpg; hl++) {
        float4 v = ((const float4*)attn_h)[(((size_t)(b * hpg + hl)) << 16) + rem];
        s.x += v.x; s.y += v.y; s.z += v.z; s.w += v.w;
    }
    float4* o = (float4*)attn_out + (((size_t)b) << 16) + rem;
    const float sc = 1.0f / (float)HH;
    float4 prev = {0.f, 0.f, 0.f, 0.f};
    if (accumulate) prev = *o;
    prev.x += s.x * sc; prev.y += s.y * sc; prev.z += s.z * sc; prev.w += s.w * sc;
    *o = prev;
}

// ---------------- MI: pdf + wsum ----------------
__global__ __launch_bounds__(256)
void wsum_kernel(const float* __restrict__ lpdf, const float* __restrict__ cp,
                 const unsigned int* __restrict__ maxenc,
                 float* __restrict__ pdf_out, float* __restrict__ wsum_out) {
    __shared__ float s_red[256];
    int t = threadIdx.x;
    int bh = blockIdx.x;
    float M = fdec(*maxenc);
    float a[CC] = {0.f, 0.f, 0.f, 0.f};
    for (int li = 0; li < 2; li++) {
        int l = t + li * 256;
        size_t idx = ((size_t)bh * LL + l) * CC;
        float p0 = expf(lpdf[idx + 0] - M);
        float p1 = expf(lpdf[idx + 1] - M);
        float p2 = expf(lpdf[idx + 2] - M);
        float p3 = expf(lpdf[idx + 3] - M);
        float pd = p0 + p1 + p2 + p3;
        pdf_out[(size_t)bh * LL + l] = pd;
        a[0] += cp[idx + 0] * pd; a[1] += cp[idx + 1] * pd;
        a[2] += cp[idx + 2] * pd; a[3] += cp[idx + 3] * pd;
    }
#pragma unroll
    for (int c = 0; c < CC; c++) {
        float tot = block_sum256(a[c], s_red);
        if (t == 0) wsum_out[bh * CC + c] = tot;
    }
}

// ---------------- MI: pairwise head overlap ----------------
__global__ __launch_bounds__(256)
void mi_kernel(const float* __restrict__ cp, const float* __restrict__ pdf,
               const float* __restrict__ wsum, float* __restrict__ mi_out) {
    __shared__ float s_q[HH * CC];
    __shared__ float s_c[HH * CC];
    __shared__ float s_red[256];
    int t = threadIdx.x;
    int b = blockIdx.x >> 9;
    int l = blockIdx.x & 511;
    if (t < HH * CC) {
        int i = t >> 2, c = t & 3;
        float cpv = cp[((size_t)(b * HH + i) * LL + l) * CC + c];
        s_c[t] = cpv;
        float w = cpv * pdf[(size_t)(b * HH + i) * LL + l];
        float ws = wsum[(b * HH + i) * CC + c];
        s_q[t] = w / fmaxf(ws, 1e-6f);
    }
    __syncthreads();
    int i = t >> 4, j = t & 15;
    float sdot = 0.f;
#pragma unroll
    for (int c = 0; c < CC; c++) sdot += s_q[i * 4 + c] * s_c[j * 4 + c];
    float mi_p = fminf(sdot, 1.f);
    float val = (i != j) ? logf(1.f - mi_p + 1e-6f) : 0.f;
    float tot = block_sum256(val, s_red);
    if (t == 0) atomicAdd(mi_out + b, -10.f * tot * (1.0f / ((float)LL * HH * HH)));
}

// ---------------- launcher ----------------
extern "C" void kernel_launch(void* const* d_in, const int* in_sizes, int n_in,
                              void* d_out, int out_size, void* d_ws, size_t ws_size,
                              hipStream_t stream) {
    (void)in_sizes; (void)n_in; (void)out_size;
    const float* query  = (const float*)d_in[0];
    const float* key    = (const float*)d_in[1];
    const float* value  = (const float*)d_in[2];
    const float* Wq     = (const float*)d_in[3];
    const float* bq     = (const float*)d_in[4];
    const float* Wk     = (const float*)d_in[5];
    const float* bk     = (const float*)d_in[6];
    const float* Wv     = (const float*)d_in[7];
    const float* bv     = (const float*)d_in[8];
    const float* Wo     = (const float*)d_in[9];
    const float* bo     = (const float*)d_in[10];
    const float* Wsem   = (const float*)d_in[11];
    const float* bsem   = (const float*)d_in[12];
    const float* Whead  = (const float*)d_in[13];
    const float* bhead  = (const float*)d_in[14];
    const float* tokmu  = (const float*)d_in[15];
    const float* toklv  = (const float*)d_in[16];
    const float* toklp  = (const float*)d_in[17];
    const float* headmu = (const float*)d_in[18];
    const float* headlv = (const float*)d_in[19];
    const float* headlp = (const float*)d_in[20];

    float* ws   = (float*)d_ws;
    const size_t NBLD = (size_t)BB * LL * DD;      // 4194304
    float* q    = ws;
    float* k    = ws + NBLD;
    float* v    = ws + 2 * NBLD;
    float* ctxf = ws + 3 * NBLD;
    float* alvq = ws + 4 * NBLD;
    float* alvh = alvq + (size_t)BB * HH * LL;
    float* cpq  = alvh + (size_t)BB * HH * LL;
    float* cph  = cpq + (size_t)BB * HH * LL * CC;
    float* lpdfh= cph + (size_t)BB * HH * LL * CC;
    float* pdfb = lpdfh + (size_t)BB * HH * LL * CC;
    float* wsumb= pdfb + (size_t)BB * HH * LL;
    unsigned int* maxenc = (unsigned int*)(wsumb + (size_t)BB * HH * CC);

    // bf16 hi/lo scratch (ushort)
    unsigned short* us = (unsigned short*)(maxenc + 4);
    const size_t WSZ = (size_t)DD * DD;            // 1048576
    unsigned short* qh = us;
    unsigned short* ql = qh + NBLD;
    unsigned short* kh = ql + NBLD;
    unsigned short* kl = kh + NBLD;
    unsigned short* vh = kl + NBLD;
    unsigned short* vl = vh + NBLD;
    unsigned short* ch = vl + NBLD;
    unsigned short* cl = ch + NBLD;
    unsigned short* wqh = cl + NBLD;
    unsigned short* wql = wqh + WSZ;
    unsigned short* wkh = wql + WSZ;
    unsigned short* wkl = wkh + WSZ;
    unsigned short* wvh = wkl + WSZ;
    unsigned short* wvl = wvh + WSZ;
    unsigned short* woh = wvl + WSZ;
    unsigned short* wol = woh + WSZ;
    float* attn_h = (float*)(wol + WSZ);

    size_t base_bytes = (size_t)((char*)attn_h - (char*)d_ws);
    int hpg = 1;
    {
        int cands[5] = {16, 8, 4, 2, 1};
        for (int i = 0; i < 5; i++) {
            size_t need = base_bytes + (size_t)BB * cands[i] * LL * LL * sizeof(float);
            if (need <= ws_size) { hpg = cands[i]; break; }
        }
    }

    float* out      = (float*)d_out;
    float* attn_out = out + NBLD;
    float* kl_out   = attn_out + (size_t)BB * LL * LL;
    float* div_out  = kl_out + BB;
    float* mi_out   = div_out + BB;

    hipMemsetAsync(kl_out, 0, 3 * BB * sizeof(float), stream);
    hipMemsetAsync(maxenc, 0, sizeof(unsigned int), stream);

    // convert inputs + weights to bf16 hi/lo (weights transposed)
    convert_hilo<<<NBLD / 1024, 256, 0, stream>>>(query, qh, ql);
    convert_hilo<<<NBLD / 1024, 256, 0, stream>>>(key,   kh, kl);
    convert_hilo<<<NBLD / 1024, 256, 0, stream>>>(value, vh, vl);
    dim3 wg(16, 16);
    wconv_kernel<<<wg, 256, 0, stream>>>(Wq, wqh, wql);
    wconv_kernel<<<wg, 256, 0, stream>>>(Wk, wkh, wkl);
    wconv_kernel<<<wg, 256, 0, stream>>>(Wv, wvh, wvl);
    wconv_kernel<<<wg, 256, 0, stream>>>(Wo, woh, wol);

    dim3 gg(DD / 128, BB * LL / 128);  // (8, 32)
    mfma_gemm_bias<<<gg, 256, 0, stream>>>(qh, ql, wqh, wql, bq, q);
    mfma_gemm_bias<<<gg, 256, 0, stream>>>(kh, kl, wkh, wkl, bk, k);
    mfma_gemm_bias<<<gg, 256, 0, stream>>>(vh, vl, wvh, wvl, bv, v);

    alv_gemm<<<BB * LL / 16, 256, 0, stream>>>(q, Wsem, bsem, alvq);
    cluster_kernel<<<BB * HH * 2, 256, 0, stream>>>(q, alvq, tokmu, toklv, toklp,
                                                    cpq, nullptr, nullptr, kl_out, 0);
    pairstats_kernel<<<BB * HH, 256, 0, stream>>>(cpq, div_out, nullptr, 0);

    for (int h0 = 0; h0 < HH; h0 += hpg) {
        attn2_kernel<<<dim3(LL / QT2, hpg, BB), 256, 0, stream>>>(
            q, k, v, cpq, ctxf, attn_h, h0, hpg);
        attn_reduce<<<BB * LL * LL / 4 / 256, 256, 0, stream>>>(
            attn_h, attn_out, hpg, h0 > 0 ? 1 : 0);
    }

    convert_hilo<<<NBLD / 1024, 256, 0, stream>>>(ctxf, ch, cl);
    alv_gemm<<<BB * LL / 16, 256, 0, stream>>>(ctxf, Whead, bhead, alvh);
    cluster_kernel<<<BB * HH * 2, 256, 0, stream>>>(ctxf, alvh, headmu, headlv, headlp,
                                                    cph, lpdfh, maxenc, kl_out, 1);
    pairstats_kernel<<<BB * HH, 256, 0, stream>>>(cph, div_out, mi_out, 1);
    wsum_kernel<<<BB * HH, 256, 0, stream>>>(lpdfh, cph, maxenc, pdfb, wsumb);
    mi_kernel<<<BB * LL, 256, 0, stream>>>(cph, pdfb, wsumb, mi_out);
    mfma_gemm_bias<<<gg, 256, 0, stream>>>(ch, cl, woh, wol, bo, out);
}